// Round 8
// baseline (303.407 us; speedup 1.0000x reference)
//
#include <hip/hip_runtime.h>
#include <hip/hip_bf16.h>

// GCN 2-layer forward on gfx950 — CSR radix partition + fp32 16B/lane gather
// (4 edges per wave-load, no cvt), self-loop folded into CSR.
//
//   layer 1: xs = dinv ⊙ x;  t[d] = dinv[d] * Σ_{s∈csr[d]} xs[s]   (self incl.)
//            h = relu(t W1 + b1)                                    (fp32 GEMM)
//   layer 2: y = dinv ⊙ (h W2) padded to 64 cols; out[d] = dinv[d]*Σ y[s] + b2
//
// R8: R7 gather was VALU-bound on fp16 unpack (62% VALUBusy; 48 of ~110
// instrs/row were cvt+fma, 48 reduction shuffles). fp32 rows, 16 lanes/row:
// 4 fma/group, zero cvt, 2-round reduction, branch-free full groups, self in
// ssrc. Bytes ~double but R6 proved this path is instruction- not byte-bound.

static constexpr int FIN = 64;
static constexpr int HID = 128;
static constexpr int CLS = 40;
static constexpr int NB_MAX = 392;   // buckets of 256 nodes; N <= 100352
static constexpr int NWG_P = 256;    // partition workgroups

// ---------------- CSR build: radix partition by dst>>8 ----------------

__global__ __launch_bounds__(1024) void k_cnt(const int* __restrict__ dst,
                                              int* __restrict__ cntmat,
                                              int E, int NB, int per_wg) {
    __shared__ int lh[NB_MAX];
    const int tid = threadIdx.x, wg = blockIdx.x;
    for (int i = tid; i < NB; i += 1024) lh[i] = 0;
    __syncthreads();
    const int r0 = wg * per_wg, r1 = min(E, r0 + per_wg);
    for (int e = r0 + tid; e < r1; e += 1024)
        atomicAdd(&lh[dst[e] >> 8], 1);
    __syncthreads();
    for (int b = tid; b < NB; b += 1024) cntmat[b * NWG_P + wg] = lh[b];
}

__global__ __launch_bounds__(256) void k_bscan1(int* __restrict__ cntmat,
                                                int* __restrict__ btot) {
    __shared__ int sd[256];
    const int b = blockIdx.x, tid = threadIdx.x;
    int v = cntmat[b * NWG_P + tid];
    sd[tid] = v;
    for (int off = 1; off < 256; off <<= 1) {
        __syncthreads();
        int t = (tid >= off) ? sd[tid - off] : 0;
        __syncthreads();
        sd[tid] += t;
    }
    __syncthreads();
    cntmat[b * NWG_P + tid] = sd[tid] - v;
    if (tid == 255) btot[b] = sd[255];
}

__global__ __launch_bounds__(512) void k_bscan2(const int* __restrict__ btot,
                                                int* __restrict__ bbase,
                                                int NB, int E) {
    __shared__ int sd[512];
    const int tid = threadIdx.x;
    int v = (tid < NB) ? btot[tid] : 0;
    sd[tid] = v;
    for (int off = 1; off < 512; off <<= 1) {
        __syncthreads();
        int t = (tid >= off) ? sd[tid - off] : 0;
        __syncthreads();
        sd[tid] += t;
    }
    __syncthreads();
    if (tid < NB) bbase[tid] = sd[tid] - v;
    if (tid == 0) bbase[NB] = E;
}

__global__ __launch_bounds__(1024) void k_scat(const int* __restrict__ ei,
                                               const int* __restrict__ cntmat,
                                               const int* __restrict__ bbase,
                                               unsigned* __restrict__ tmp,
                                               int E, int NB, int per_wg) {
    __shared__ int lcur[NB_MAX];
    const int tid = threadIdx.x, wg = blockIdx.x;
    for (int b = tid; b < NB; b += 1024)
        lcur[b] = cntmat[b * NWG_P + wg] + bbase[b];
    __syncthreads();
    const int r0 = wg * per_wg, r1 = min(E, r0 + per_wg);
    for (int e = r0 + tid; e < r1; e += 1024) {
        int s = ei[e], d = ei[E + e];
        int b = d >> 8;
        int pos = atomicAdd(&lcur[b], 1);
        tmp[pos] = ((unsigned)(d & 255) << 24) | (unsigned)s;
    }
}

// P2: one WG per bucket. Emits SELF-INCLUSIVE adjacency: node's list is
// [node, neighbors...]; rstart/cnt shifted accordingly (ssrc has E+N ints).
__global__ __launch_bounds__(256) void k_p2(const unsigned* __restrict__ tmp,
                                            const int* __restrict__ bbase,
                                            int* __restrict__ rstart,
                                            int* __restrict__ cnt,
                                            float* __restrict__ dinv,
                                            int* __restrict__ ssrc, int N) {
    __shared__ int nh[256];
    __shared__ int sd[256];
    __shared__ int curs[256];
    const int tid = threadIdx.x;
    const int b = blockIdx.x;
    const int node0 = b << 8;
    const int e0 = bbase[b], e1 = bbase[b + 1];
    nh[tid] = 0;
    __syncthreads();
    for (int e = e0 + tid; e < e1; e += 256)
        atomicAdd(&nh[tmp[e] >> 24], 1);
    __syncthreads();
    int v = nh[tid];
    sd[tid] = v;
    for (int off = 1; off < 256; off <<= 1) {
        __syncthreads();
        int t = (tid >= off) ? sd[tid - off] : 0;
        __syncthreads();
        sd[tid] += t;
    }
    __syncthreads();
    // +node0+tid: one self slot per preceding node (all dsts in bucket < N)
    int rs = e0 + node0 + (sd[tid] - v) + tid;
    int node = node0 + tid;
    if (node < N) {
        rstart[node] = rs;
        cnt[node] = v + 1;                 // self-inclusive
        dinv[node] = rsqrtf((float)v + 1.0f);
        ssrc[rs] = node;                   // self entry
    }
    curs[tid] = rs + 1;
    __syncthreads();
    for (int e = e0 + tid; e < e1; e += 256) {
        unsigned p = tmp[e];
        int slot = atomicAdd(&curs[p >> 24], 1);
        ssrc[slot] = (int)(p & 0xFFFFFFu);
    }
}

// xs = dinv ⊙ x (fp32), float4 per thread.
__global__ __launch_bounds__(256) void k_prescale(const float* __restrict__ x,
                                                  const float* __restrict__ dinv,
                                                  float* __restrict__ xs, int N) {
    int idx = blockIdx.x * 256 + threadIdx.x;   // over N*16
    if (idx >= N * 16) return;
    int i = idx >> 4;
    float dv = dinv[i];
    float4 v = *(const float4*)&x[(size_t)idx * 4];
    v.x *= dv; v.y *= dv; v.z *= dv; v.w *= dv;
    *(float4*)&xs[(size_t)idx * 4] = v;
}

// ---------------- packed fp32 gather-aggregate ----------------
// X: fp32 rows of 64 floats (256B, pre-scaled). One wave per dst row.
// Lane l: edge-slot group grp=l>>4, 16B chunk sub=l&15. One dwordx4 covers
// 4 edge rows. Full groups are branch-free; tail masked. 2-round reduction.
// out[d][f<FOUT] = dinv[d] * sum + bias[f]

template <int FOUT, bool BIAS>
__global__ __launch_bounds__(256) void k_gather32(const float* __restrict__ X,
                                                  const float* __restrict__ dinv,
                                                  const int* __restrict__ rstart,
                                                  const int* __restrict__ cnt,
                                                  const int* __restrict__ ssrc,
                                                  const float* __restrict__ bias,
                                                  float* __restrict__ out, int N) {
    const int wid = (blockIdx.x * 256 + threadIdx.x) >> 6;
    const int lane = threadIdx.x & 63;
    if (wid >= N) return;
    const int grp = lane >> 4, sub = lane & 15;
    const float dv = dinv[wid];
    const int st = rstart[wid];
    const int total = cnt[wid];            // self-inclusive
    float4 acc = make_float4(0.f, 0.f, 0.f, 0.f);
    for (int base = 0; base < total; base += 64) {
        const int m = min(64, total - base);
        const int myS = (lane < m) ? ssrc[st + base + lane] : 0;
        const int gfull = m >> 2;
#pragma unroll 4
        for (int g = 0; g < gfull; ++g) {
            const int s = __shfl(myS, g * 4 + grp);
            const float4 v = *(const float4*)(X + ((size_t)s << 6) + (sub << 2));
            acc.x += v.x; acc.y += v.y; acc.z += v.z; acc.w += v.w;
        }
        if (m & 3) {
            const int slot = gfull * 4 + grp;
            const int s = __shfl(myS, min(slot, m - 1));
            const float w = (slot < m) ? 1.f : 0.f;
            const float4 v = *(const float4*)(X + ((size_t)s << 6) + (sub << 2));
            acc.x = fmaf(w, v.x, acc.x); acc.y = fmaf(w, v.y, acc.y);
            acc.z = fmaf(w, v.z, acc.z); acc.w = fmaf(w, v.w, acc.w);
        }
    }
    acc.x += __shfl_xor(acc.x, 16); acc.y += __shfl_xor(acc.y, 16);
    acc.z += __shfl_xor(acc.z, 16); acc.w += __shfl_xor(acc.w, 16);
    acc.x += __shfl_xor(acc.x, 32); acc.y += __shfl_xor(acc.y, 32);
    acc.z += __shfl_xor(acc.z, 32); acc.w += __shfl_xor(acc.w, 32);
    const int f0 = sub * 4;
    if (grp == 0 && (FOUT == 64 || f0 < FOUT)) {
        float4 o = make_float4(acc.x * dv, acc.y * dv, acc.z * dv, acc.w * dv);
        if (BIAS) {
            float4 bb = *(const float4*)&bias[f0];
            o.x += bb.x; o.y += bb.y; o.z += bb.z; o.w += bb.w;
        }
        *(float4*)&out[(size_t)wid * FOUT + f0] = o;
    }
}

// ---------------- GEMMs ----------------

// h = relu(t @ W1 + b1), 64-row tile, TM=8 x TN=4 (fp32).
__global__ __launch_bounds__(256, 3) void k_gemm1(const float* __restrict__ A,
                                                  const float* __restrict__ W,
                                                  const float* __restrict__ bias,
                                                  float* __restrict__ H, int N) {
    __shared__ float Bs[FIN][132];
    __shared__ float As[64][68];
    const int tid = threadIdx.x;
    {
        const float4* W4 = (const float4*)W;
        for (int i = tid; i < 2048; i += 256) {
            int r = i >> 5, c4 = i & 31;
            *(float4*)&Bs[r][c4 * 4] = W4[i];
        }
    }
    const int row0 = blockIdx.x * 64;
    for (int i = tid; i < 1024; i += 256) {
        int r = i >> 4, c4 = i & 15;
        int gr = row0 + r;
        float4 v = make_float4(0.f, 0.f, 0.f, 0.f);
        if (gr < N) v = *(const float4*)&A[(size_t)gr * FIN + c4 * 4];
        *(float4*)&As[r][c4 * 4] = v;
    }
    __syncthreads();
    const int tc = tid & 31;
    const int tr = tid >> 5;
    float acc[8][4] = {};
#pragma unroll 2
    for (int k = 0; k < FIN; k += 4) {
        float4 bq[4];
#pragma unroll
        for (int kk = 0; kk < 4; ++kk) bq[kk] = *(const float4*)&Bs[k + kk][tc * 4];
#pragma unroll
        for (int i = 0; i < 8; ++i) {
            float4 a = *(const float4*)&As[tr * 8 + i][k];
            float* ac = acc[i];
            ac[0] = fmaf(a.x, bq[0].x, ac[0]); ac[0] = fmaf(a.y, bq[1].x, ac[0]);
            ac[0] = fmaf(a.z, bq[2].x, ac[0]); ac[0] = fmaf(a.w, bq[3].x, ac[0]);
            ac[1] = fmaf(a.x, bq[0].y, ac[1]); ac[1] = fmaf(a.y, bq[1].y, ac[1]);
            ac[1] = fmaf(a.z, bq[2].y, ac[1]); ac[1] = fmaf(a.w, bq[3].y, ac[1]);
            ac[2] = fmaf(a.x, bq[0].z, ac[2]); ac[2] = fmaf(a.y, bq[1].z, ac[2]);
            ac[2] = fmaf(a.z, bq[2].z, ac[2]); ac[2] = fmaf(a.w, bq[3].z, ac[2]);
            ac[3] = fmaf(a.x, bq[0].w, ac[3]); ac[3] = fmaf(a.y, bq[1].w, ac[3]);
            ac[3] = fmaf(a.z, bq[2].w, ac[3]); ac[3] = fmaf(a.w, bq[3].w, ac[3]);
        }
    }
    float4 bv = *(const float4*)&bias[tc * 4];
#pragma unroll
    for (int i = 0; i < 8; ++i) {
        int gr = row0 + tr * 8 + i;
        if (gr < N) {
            float4 v;
            v.x = fmaxf(acc[i][0] + bv.x, 0.f);
            v.y = fmaxf(acc[i][1] + bv.y, 0.f);
            v.z = fmaxf(acc[i][2] + bv.z, 0.f);
            v.w = fmaxf(acc[i][3] + bv.w, 0.f);
            *(float4*)&H[(size_t)gr * HID + tc * 4] = v;
        }
    }
}

// y = dinv ⊙ (h @ W2) into fp32 rows padded to 64 cols (pad zeroed).
__global__ __launch_bounds__(256, 4) void k_gemm2(const float* __restrict__ H,
                                                  const float* __restrict__ W,
                                                  const float* __restrict__ dinv,
                                                  float* __restrict__ Y, int N) {
    __shared__ float Bs[CLS][132];
    const int tid = threadIdx.x;
    for (int i = tid; i < HID * CLS; i += 256) {
        int k = i / CLS, c = i - k * CLS;
        Bs[c][k] = W[i];
    }
    __syncthreads();
    const int row0 = blockIdx.x * 64;
    const int tc = tid & 7;
    const int tr = tid >> 3;
    const int r0 = row0 + tr * 2;
    const int ra = min(r0, N - 1);
    const int rb = min(r0 + 1, N - 1);
    float acc[2][5] = {};
#pragma unroll 2
    for (int k = 0; k < HID; k += 4) {
        float4 b[5];
#pragma unroll
        for (int j = 0; j < 5; ++j) b[j] = *(const float4*)&Bs[tc * 5 + j][k];
        float4 a0 = *(const float4*)&H[(size_t)ra * HID + k];
        float4 a1 = *(const float4*)&H[(size_t)rb * HID + k];
#pragma unroll
        for (int j = 0; j < 5; ++j) {
            acc[0][j] = fmaf(a0.x, b[j].x, fmaf(a0.y, b[j].y,
                        fmaf(a0.z, b[j].z, fmaf(a0.w, b[j].w, acc[0][j]))));
            acc[1][j] = fmaf(a1.x, b[j].x, fmaf(a1.y, b[j].y,
                        fmaf(a1.z, b[j].z, fmaf(a1.w, b[j].w, acc[1][j]))));
        }
    }
    float dva = dinv[ra], dvb = dinv[rb];
#pragma unroll
    for (int i = 0; i < 2; ++i) {
        int gr = r0 + i;
        float dv = (i == 0) ? dva : dvb;
        if (gr < N) {
#pragma unroll
            for (int j = 0; j < 5; ++j)
                Y[(size_t)gr * 64 + tc * 5 + j] = acc[i][j] * dv;
        }
    }
    // zero pad cols 40..63 (6 float4 per row)
    for (int i = tid; i < 64 * 6; i += 256) {
        int r = row0 + i / 6, c4 = 10 + i % 6;
        if (r < N) *(float4*)&Y[(size_t)r * 64 + c4 * 4] =
            make_float4(0.f, 0.f, 0.f, 0.f);
    }
}

// ---------------- launch ----------------

extern "C" void kernel_launch(void* const* d_in, const int* in_sizes, int n_in,
                              void* d_out, int out_size, void* d_ws, size_t ws_size,
                              hipStream_t stream) {
    const float* x  = (const float*)d_in[0];
    const int*   ei = (const int*)d_in[1];   // [2][E]
    const float* W1 = (const float*)d_in[2];
    const float* b1 = (const float*)d_in[3];
    const float* W2 = (const float*)d_in[4];
    const float* b2 = (const float*)d_in[5];
    float* out = (float*)d_out;

    const int N = in_sizes[0] / FIN;
    const int E = in_sizes[1] / 2;
    const int NB = (N + 255) >> 8;
    const int per_wg = (E + NWG_P - 1) / NWG_P;

    float* dinv   = (float*)d_ws;                  // N
    float* t      = dinv + N;                      // N*64 f32 (reused as y padded)
    float* h      = t + (size_t)N * FIN;           // N*HID f32 (tmp/xs overlap)
    int* cnt      = (int*)(h + (size_t)N * HID);   // N
    int* rstart   = cnt + N;                       // N
    int* ssrc     = rstart + N;                    // E + N (self-inclusive)
    int* cntmat   = ssrc + E + N;                  // NB_MAX*NWG_P
    int* btot     = cntmat + NB_MAX * NWG_P;       // NB_MAX
    int* bbase    = btot + NB_MAX;                 // NB_MAX+1
    unsigned* tmp = (unsigned*)h;                  // E words (dead after p2)
    float* xs     = h;                             // N*64 f32 (dead before gemm1)
    float* y      = t;                             // N*64 f32 padded (after gemm1)

    dim3 blk(256);
    // CSR build: radix partition by dst
    hipLaunchKernelGGL(k_cnt,    dim3(NWG_P), dim3(1024), 0, stream, ei + E, cntmat, E, NB, per_wg);
    hipLaunchKernelGGL(k_bscan1, dim3(NB), blk, 0, stream, cntmat, btot);
    hipLaunchKernelGGL(k_bscan2, dim3(1), dim3(512), 0, stream, btot, bbase, NB, E);
    hipLaunchKernelGGL(k_scat,   dim3(NWG_P), dim3(1024), 0, stream, ei, cntmat, bbase, tmp, E, NB, per_wg);
    hipLaunchKernelGGL(k_p2,     dim3(NB), blk, 0, stream, tmp, bbase, rstart, cnt, dinv, ssrc, N);
    // layer 1: prescale (fp32) -> packed gather -> fp32 GEMM+bias+relu
    hipLaunchKernelGGL(k_prescale, dim3((N * 16 + 255) / 256), blk, 0, stream, x, dinv, xs, N);
    hipLaunchKernelGGL((k_gather32<FIN, false>), dim3((N + 3) / 4), blk, 0, stream,
                       xs, dinv, rstart, cnt, ssrc, (const float*)nullptr, t, N);
    hipLaunchKernelGGL(k_gemm1, dim3((N + 63) / 64), blk, 0, stream, t, W1, b1, h, N);
    // layer 2: GEMM (scaled, padded fp32) -> packed gather + bias
    hipLaunchKernelGGL(k_gemm2, dim3((N + 63) / 64), blk, 0, stream, h, W2, dinv, y, N);
    hipLaunchKernelGGL((k_gather32<CLS, true>), dim3((N + 3) / 4), blk, 0, stream,
                       y, dinv, rstart, cnt, ssrc, b2, out, N);
}

// Round 9
// 230.153 us; speedup vs baseline: 1.3183x; 1.3183x over previous
//
#include <hip/hip_runtime.h>
#include <hip/hip_bf16.h>

// GCN 2-layer forward on gfx950 — CSR radix partition, fp16 packed gathers,
// fused fp16-MFMA MLP (t -> h -> y with h kept on-chip).
//
//   xh = fp16(dinv ⊙ x)
//   t  = fp16( dinv[d] * Σ_{s∈csr[d]} xh[s] )          (gather, self-inclusive)
//   h  = relu(t W1 + b1)   [MFMA, C-frags in regs]     (k_mlp phase 1)
//   yh = fp16(dinv ⊙ (h W2))  padded to 64 cols        (k_mlp phase 2)
//   out[d] = dinv[d] * Σ yh[s] + b2                    (gather)
//
// R9: R7/R8 showed gather is VALU-bound at fp16 (50us) and fetch-bound at
// fp32 (62us) -> keep fp16 gathers. GEMMs (~60us fp32 VALU + 100MB h
// round-trip) replaced by one MFMA kernel: per wave 16 rows, 16x16x32_f16,
// h transposed C->A layout via XOR-swizzled LDS (16KB/WG). W1/W2 prepped
// into fragment-ordered fp16 buffers (L2-resident).

static constexpr int FIN = 64;
static constexpr int HID = 128;
static constexpr int CLS = 40;
static constexpr int NB_MAX = 392;   // buckets of 256 nodes; N <= 100352
static constexpr int NWG_P = 256;    // partition workgroups

typedef _Float16 half8 __attribute__((ext_vector_type(8)));
typedef _Float16 half4v __attribute__((ext_vector_type(4)));
typedef float floatx4 __attribute__((ext_vector_type(4)));

// ---------------- CSR build: radix partition by dst>>8 ----------------

__global__ __launch_bounds__(1024) void k_cnt(const int* __restrict__ dst,
                                              int* __restrict__ cntmat,
                                              int E, int NB, int per_wg) {
    __shared__ int lh[NB_MAX];
    const int tid = threadIdx.x, wg = blockIdx.x;
    for (int i = tid; i < NB; i += 1024) lh[i] = 0;
    __syncthreads();
    const int r0 = wg * per_wg, r1 = min(E, r0 + per_wg);
    for (int e = r0 + tid; e < r1; e += 1024)
        atomicAdd(&lh[dst[e] >> 8], 1);
    __syncthreads();
    for (int b = tid; b < NB; b += 1024) cntmat[b * NWG_P + wg] = lh[b];
}

__global__ __launch_bounds__(256) void k_bscan1(int* __restrict__ cntmat,
                                                int* __restrict__ btot) {
    __shared__ int sd[256];
    const int b = blockIdx.x, tid = threadIdx.x;
    int v = cntmat[b * NWG_P + tid];
    sd[tid] = v;
    for (int off = 1; off < 256; off <<= 1) {
        __syncthreads();
        int t = (tid >= off) ? sd[tid - off] : 0;
        __syncthreads();
        sd[tid] += t;
    }
    __syncthreads();
    cntmat[b * NWG_P + tid] = sd[tid] - v;
    if (tid == 255) btot[b] = sd[255];
}

__global__ __launch_bounds__(512) void k_bscan2(const int* __restrict__ btot,
                                                int* __restrict__ bbase,
                                                int NB, int E) {
    __shared__ int sd[512];
    const int tid = threadIdx.x;
    int v = (tid < NB) ? btot[tid] : 0;
    sd[tid] = v;
    for (int off = 1; off < 512; off <<= 1) {
        __syncthreads();
        int t = (tid >= off) ? sd[tid - off] : 0;
        __syncthreads();
        sd[tid] += t;
    }
    __syncthreads();
    if (tid < NB) bbase[tid] = sd[tid] - v;
    if (tid == 0) bbase[NB] = E;
}

__global__ __launch_bounds__(1024) void k_scat(const int* __restrict__ ei,
                                               const int* __restrict__ cntmat,
                                               const int* __restrict__ bbase,
                                               unsigned* __restrict__ tmp,
                                               int E, int NB, int per_wg) {
    __shared__ int lcur[NB_MAX];
    const int tid = threadIdx.x, wg = blockIdx.x;
    for (int b = tid; b < NB; b += 1024)
        lcur[b] = cntmat[b * NWG_P + wg] + bbase[b];
    __syncthreads();
    const int r0 = wg * per_wg, r1 = min(E, r0 + per_wg);
    for (int e = r0 + tid; e < r1; e += 1024) {
        int s = ei[e], d = ei[E + e];
        int b = d >> 8;
        int pos = atomicAdd(&lcur[b], 1);
        tmp[pos] = ((unsigned)(d & 255) << 24) | (unsigned)s;
    }
}

// P2: one WG per bucket. Self-inclusive adjacency: node's list = [node, nbrs].
__global__ __launch_bounds__(256) void k_p2(const unsigned* __restrict__ tmp,
                                            const int* __restrict__ bbase,
                                            int* __restrict__ rstart,
                                            int* __restrict__ cnt,
                                            float* __restrict__ dinv,
                                            int* __restrict__ ssrc, int N) {
    __shared__ int nh[256];
    __shared__ int sd[256];
    __shared__ int curs[256];
    const int tid = threadIdx.x;
    const int b = blockIdx.x;
    const int node0 = b << 8;
    const int e0 = bbase[b], e1 = bbase[b + 1];
    nh[tid] = 0;
    __syncthreads();
    for (int e = e0 + tid; e < e1; e += 256)
        atomicAdd(&nh[tmp[e] >> 24], 1);
    __syncthreads();
    int v = nh[tid];
    sd[tid] = v;
    for (int off = 1; off < 256; off <<= 1) {
        __syncthreads();
        int t = (tid >= off) ? sd[tid - off] : 0;
        __syncthreads();
        sd[tid] += t;
    }
    __syncthreads();
    int rs = e0 + node0 + (sd[tid] - v) + tid;
    int node = node0 + tid;
    if (node < N) {
        rstart[node] = rs;
        cnt[node] = v + 1;                 // self-inclusive
        dinv[node] = rsqrtf((float)v + 1.0f);
        ssrc[rs] = node;                   // self entry
    }
    curs[tid] = rs + 1;
    __syncthreads();
    for (int e = e0 + tid; e < e1; e += 256) {
        unsigned p = tmp[e];
        int slot = atomicAdd(&curs[p >> 24], 1);
        ssrc[slot] = (int)(p & 0xFFFFFFu);
    }
}

// xh = fp16(dinv ⊙ x): 4 elems per thread.
__global__ __launch_bounds__(256) void k_prescale(const float* __restrict__ x,
                                                  const float* __restrict__ dinv,
                                                  _Float16* __restrict__ xh, int N) {
    int idx = blockIdx.x * 256 + threadIdx.x;   // over N*16
    if (idx >= N * 16) return;
    int i = idx >> 4;
    float dv = dinv[i];
    float4 v = *(const float4*)&x[(size_t)idx * 4];
    half4v o;
    o[0] = (_Float16)(dv * v.x); o[1] = (_Float16)(dv * v.y);
    o[2] = (_Float16)(dv * v.z); o[3] = (_Float16)(dv * v.w);
    *(half4v*)(xh + (size_t)idx * 4) = o;
}

// Prep W1/W2 into MFMA B-fragment-ordered fp16 buffers.
// B frag (16x16x32): lane holds B[k = quad*8+j][n = (lane&15)], j=0..7.
__global__ __launch_bounds__(256) void k_prep(const float* __restrict__ W1,
                                              const float* __restrict__ W2,
                                              _Float16* __restrict__ w1f,
                                              _Float16* __restrict__ w2f) {
    const int idx = blockIdx.x * 256 + threadIdx.x;
    if (idx < 1024) {                       // W1: nt 0..7, kk 0..1, lane
        const int lane = idx & 63;
        const int kk = (idx >> 6) & 1;
        const int nt = idx >> 7;
        const int quad = lane >> 4, col = lane & 15;
        half8 o;
#pragma unroll
        for (int j = 0; j < 8; ++j) {
            const int k = kk * 32 + quad * 8 + j;
            const int n = nt * 16 + col;
            o[j] = (_Float16)W1[k * HID + n];
        }
        *(half8*)(w1f + (size_t)idx * 8) = o;
    } else if (idx < 1024 + 768) {          // W2: nt 0..2, kk 0..3, lane (n pad 48)
        const int i2 = idx - 1024;
        const int lane = i2 & 63;
        const int kk = (i2 >> 6) & 3;
        const int nt = i2 >> 8;
        const int quad = lane >> 4, col = lane & 15;
        half8 o;
#pragma unroll
        for (int j = 0; j < 8; ++j) {
            const int k = kk * 32 + quad * 8 + j;
            const int n = nt * 16 + col;
            o[j] = (n < CLS) ? (_Float16)W2[k * CLS + n] : (_Float16)0.f;
        }
        *(half8*)(w2f + (size_t)i2 * 8) = o;
    }
}

// ---------------- packed fp16 gather (R7 structure, self-inclusive) ---------
// X: fp16 rows of 64 halves (128B). One wave per dst row. Lane l: edge-slot
// group grp=l>>3, 16B chunk sub=l&7; one dwordx4 covers 8 edge rows.
// HALF_OUT: out = fp16 row of 64 (for MFMA A). Else fp32 FOUT cols (+bias).

template <bool HALF_OUT, int FOUT, bool BIAS>
__global__ __launch_bounds__(256) void k_gather16(const _Float16* __restrict__ X,
                                                  const float* __restrict__ dinv,
                                                  const int* __restrict__ rstart,
                                                  const int* __restrict__ cnt,
                                                  const int* __restrict__ ssrc,
                                                  const float* __restrict__ bias,
                                                  void* __restrict__ outv, int N) {
    const int wid = (blockIdx.x * 256 + threadIdx.x) >> 6;
    const int lane = threadIdx.x & 63;
    if (wid >= N) return;
    const int grp = lane >> 3, sub = lane & 7;
    const float dv = dinv[wid];
    const int st = rstart[wid];
    const int total = cnt[wid];            // self-inclusive
    float acc[8] = {0.f, 0.f, 0.f, 0.f, 0.f, 0.f, 0.f, 0.f};
    for (int base = 0; base < total; base += 64) {
        const int m = min(64, total - base);
        const int myS = (lane < m) ? ssrc[st + base + lane] : 0;
        const int gmax = (m + 7) >> 3;
#pragma unroll 4
        for (int g = 0; g < gmax; ++g) {
            const int slot = g * 8 + grp;
            const int s = __shfl(myS, min(slot, m - 1));
            const float w = (slot < m) ? 1.f : 0.f;
            const half8 hv = *(const half8*)(X + ((size_t)s << 6) + (sub << 3));
#pragma unroll
            for (int k = 0; k < 8; ++k)
                acc[k] = fmaf(w, (float)hv[k], acc[k]);
        }
    }
#pragma unroll
    for (int k = 0; k < 8; ++k) {
        acc[k] += __shfl_xor(acc[k], 8);
        acc[k] += __shfl_xor(acc[k], 16);
        acc[k] += __shfl_xor(acc[k], 32);
    }
    if (HALF_OUT) {
        if (grp == 0) {                    // lanes 0..7 write feats sub*8..+7
            half8 o;
#pragma unroll
            for (int k = 0; k < 8; ++k) o[k] = (_Float16)(acc[k] * dv);
            *(half8*)((_Float16*)outv + ((size_t)wid << 6) + (sub << 3)) = o;
        }
    } else {
        const int f0 = sub * 8 + (grp & 1) * 4;
        if (grp < 2 && f0 < FOUT) {
            const int k0 = (grp & 1) * 4;
            float4 o = make_float4(acc[k0] * dv, acc[k0 + 1] * dv,
                                   acc[k0 + 2] * dv, acc[k0 + 3] * dv);
            if (BIAS) {
                float4 bb = *(const float4*)&bias[f0];
                o.x += bb.x; o.y += bb.y; o.z += bb.z; o.w += bb.w;
            }
            *(float4*)((float*)outv + (size_t)wid * FOUT + f0) = o;
        }
    }
}

// ---------------- fused MFMA MLP: t -> h (regs) -> yh ----------------
// Wave w owns rows row0 = blk*64 + w*16 .. +15. Phase1: 8 n-tiles x 2 k-steps
// of 16x16x32_f16 -> h C-frags; bias+relu; store to XOR-swizzled LDS in
// A-layout. Phase2: 3 n-tiles x 4 k-steps -> y; dinv scale; fp16 store padded.

__global__ __launch_bounds__(256, 3) void k_mlp(const _Float16* __restrict__ th,
                                                const _Float16* __restrict__ w1f,
                                                const float* __restrict__ b1,
                                                const _Float16* __restrict__ w2f,
                                                const float* __restrict__ dinv,
                                                _Float16* __restrict__ yh, int N) {
    __shared__ _Float16 hbuf[4][16 * 128];  // 16 KB
    const int tid = threadIdx.x;
    const int wave = tid >> 6, lane = tid & 63;
    const int quad = lane >> 4, col = lane & 15;
    const int row0 = blockIdx.x * 64 + wave * 16;
    const int arow = min(row0 + col, N - 1);
    const half8 a0 = *(const half8*)(th + ((size_t)arow << 6) + quad * 8);
    const half8 a1 = *(const half8*)(th + ((size_t)arow << 6) + 32 + quad * 8);
    floatx4 c[8];
#pragma unroll
    for (int nt = 0; nt < 8; ++nt) {
        c[nt] = (floatx4){0.f, 0.f, 0.f, 0.f};
        const half8 bb0 = *(const half8*)(w1f + (size_t)((nt * 2 + 0) * 64 + lane) * 8);
        const half8 bb1 = *(const half8*)(w1f + (size_t)((nt * 2 + 1) * 64 + lane) * 8);
        c[nt] = __builtin_amdgcn_mfma_f32_16x16x32_f16(a0, bb0, c[nt], 0, 0, 0);
        c[nt] = __builtin_amdgcn_mfma_f32_16x16x32_f16(a1, bb1, c[nt], 0, 0, 0);
    }
    // bias + relu, C-layout (row=quad*4+reg, col) -> swizzled LDS (A-layout src)
    _Float16* hb = hbuf[wave];
#pragma unroll
    for (int nt = 0; nt < 8; ++nt) {
        const float bv = b1[nt * 16 + col];
#pragma unroll
        for (int reg = 0; reg < 4; ++reg) {
            const int r = quad * 4 + reg;
            const int hcol = nt * 16 + col;
            const int chunk = ((hcol >> 3) ^ r) & 15;
            hb[r * 128 + chunk * 8 + (hcol & 7)] =
                (_Float16)fmaxf(c[nt][reg] + bv, 0.f);
        }
    }
    __syncthreads();
    // phase 2: A rows m=col from LDS
    half8 a2[4];
#pragma unroll
    for (int kk = 0; kk < 4; ++kk) {
        const int chunk = ((kk * 4 + quad) ^ col) & 15;
        a2[kk] = *(const half8*)(hb + col * 128 + chunk * 8);
    }
    floatx4 c2[3];
#pragma unroll
    for (int nt = 0; nt < 3; ++nt) {
        c2[nt] = (floatx4){0.f, 0.f, 0.f, 0.f};
#pragma unroll
        for (int kk = 0; kk < 4; ++kk) {
            const half8 bb = *(const half8*)(w2f + (size_t)((nt * 4 + kk) * 64 + lane) * 8);
            c2[nt] = __builtin_amdgcn_mfma_f32_16x16x32_f16(a2[kk], bb, c2[nt], 0, 0, 0);
        }
    }
    // epilogue: dinv scale, fp16 store (cols 0..39), zero pad 40..63
#pragma unroll
    for (int reg = 0; reg < 4; ++reg) {
        const int gr = row0 + quad * 4 + reg;
        const float dvr = dinv[min(gr, N - 1)];
#pragma unroll
        for (int nt = 0; nt < 3; ++nt) {
            const int cc = nt * 16 + col;
            if (gr < N && cc < CLS)
                yh[((size_t)gr << 6) + cc] = (_Float16)(c2[nt][reg] * dvr);
        }
    }
    for (int i = lane; i < 16 * 12; i += 64) {
        const int row = row0 + i / 12;
        if (row < N)
            ((unsigned*)(yh + ((size_t)row << 6)))[20 + i % 12] = 0u;
    }
}

// ---------------- launch ----------------

extern "C" void kernel_launch(void* const* d_in, const int* in_sizes, int n_in,
                              void* d_out, int out_size, void* d_ws, size_t ws_size,
                              hipStream_t stream) {
    const float* x  = (const float*)d_in[0];
    const int*   ei = (const int*)d_in[1];   // [2][E]
    const float* W1 = (const float*)d_in[2];
    const float* b1 = (const float*)d_in[3];
    const float* W2 = (const float*)d_in[4];
    const float* b2 = (const float*)d_in[5];
    float* out = (float*)d_out;

    const int N = in_sizes[0] / FIN;
    const int E = in_sizes[1] / 2;
    const int NB = (N + 255) >> 8;
    const int per_wg = (E + NWG_P - 1) / NWG_P;

    float* dinv    = (float*)d_ws;                       // N
    _Float16* th   = (_Float16*)(dinv + N);              // N*64
    _Float16* yh   = th + (size_t)N * 64;                // N*64
    _Float16* xh   = yh + (size_t)N * 64;                // N*64
    int* cnt       = (int*)(xh + (size_t)N * 64);        // N
    int* rstart    = cnt + N;                            // N
    int* ssrc      = rstart + N;                         // E + N
    int* cntmat    = ssrc + E + N;                       // NB_MAX*NWG_P
    int* btot      = cntmat + NB_MAX * NWG_P;            // NB_MAX
    int* bbase     = btot + NB_MAX;                      // NB_MAX+1
    unsigned* tmp  = (unsigned*)(bbase + NB_MAX + 1);    // E
    _Float16* w1f  = (_Float16*)(tmp + E);               // 8192
    _Float16* w2f  = w1f + 8192;                         // 6144

    dim3 blk(256);
    // CSR build
    hipLaunchKernelGGL(k_cnt,    dim3(NWG_P), dim3(1024), 0, stream, ei + E, cntmat, E, NB, per_wg);
    hipLaunchKernelGGL(k_bscan1, dim3(NB), blk, 0, stream, cntmat, btot);
    hipLaunchKernelGGL(k_bscan2, dim3(1), dim3(512), 0, stream, btot, bbase, NB, E);
    hipLaunchKernelGGL(k_scat,   dim3(NWG_P), dim3(1024), 0, stream, ei, cntmat, bbase, tmp, E, NB, per_wg);
    hipLaunchKernelGGL(k_p2,     dim3(NB), blk, 0, stream, tmp, bbase, rstart, cnt, dinv, ssrc, N);
    // weight prep (fragment-ordered fp16)
    hipLaunchKernelGGL(k_prep, dim3(7), blk, 0, stream, W1, W2, w1f, w2f);
    // layer 1: prescale -> packed fp16 gather (fp16 out)
    hipLaunchKernelGGL(k_prescale, dim3((N * 16 + 255) / 256), blk, 0, stream, x, dinv, xh, N);
    hipLaunchKernelGGL((k_gather16<true, FIN, false>), dim3((N + 3) / 4), blk, 0, stream,
                       xh, dinv, rstart, cnt, ssrc, (const float*)nullptr, (void*)th, N);
    // fused MFMA MLP: t -> h -> yh
    hipLaunchKernelGGL(k_mlp, dim3((N + 63) / 64), blk, 0, stream, th, w1f, b1, w2f, dinv, yh, N);
    // layer 2 aggregate + bias -> out
    hipLaunchKernelGGL((k_gather16<false, CLS, true>), dim3((N + 3) / 4), blk, 0, stream,
                       yh, dinv, rstart, cnt, ssrc, b2, (void*)out, N);
}

// Round 10
// 223.783 us; speedup vs baseline: 1.3558x; 1.0285x over previous
//
#include <hip/hip_runtime.h>
#include <hip/hip_bf16.h>

// GCN 2-layer forward on gfx950 — CSR radix partition, packed-fp16 gathers,
// fused fp16-MFMA MLP (h stays on-chip).
//
//   xh = fp16(dinv ⊙ x)
//   t  = fp16( dinv[d] * Σ_{s∈csr[d]} xh[s] )          (gather, self-inclusive)
//   h  = relu(t W1 + b1)   [MFMA, C-frags in regs]     (k_mlp phase 1)
//   yh = fp16(dinv ⊙ (h W2))  padded to 64 cols        (k_mlp phase 2)
//   out[d] = dinv[d] * Σ yh[s] + b2                    (gather)
//
// R10: R9 gathers were VALU-bound (59% busy, ~360 cyc/row: 16 cvt+fma per
// 8-edge group + 48-op fp32 reduction + 64b addressing). Now: v_pk_add_f16
// accumulation (4 packed ops/group), packed half2 shfl_xor reduction,
// ssrc holds BYTE offsets (node<<7) so addressing is base+32b-offset.
// fp32 conversion only in the per-row epilogue.

static constexpr int FIN = 64;
static constexpr int HID = 128;
static constexpr int CLS = 40;
static constexpr int NB_MAX = 392;   // buckets of 256 nodes; N <= 100352
static constexpr int NWG_P = 256;    // partition workgroups

typedef _Float16 half8 __attribute__((ext_vector_type(8)));
typedef _Float16 half4v __attribute__((ext_vector_type(4)));
typedef _Float16 half2v __attribute__((ext_vector_type(2)));
typedef float floatx4 __attribute__((ext_vector_type(4)));

// ---------------- CSR build: radix partition by dst>>8 ----------------

__global__ __launch_bounds__(1024) void k_cnt(const int* __restrict__ dst,
                                              int* __restrict__ cntmat,
                                              int E, int NB, int per_wg) {
    __shared__ int lh[NB_MAX];
    const int tid = threadIdx.x, wg = blockIdx.x;
    for (int i = tid; i < NB; i += 1024) lh[i] = 0;
    __syncthreads();
    const int r0 = wg * per_wg, r1 = min(E, r0 + per_wg);
    for (int e = r0 + tid; e < r1; e += 1024)
        atomicAdd(&lh[dst[e] >> 8], 1);
    __syncthreads();
    for (int b = tid; b < NB; b += 1024) cntmat[b * NWG_P + wg] = lh[b];
}

__global__ __launch_bounds__(256) void k_bscan1(int* __restrict__ cntmat,
                                                int* __restrict__ btot) {
    __shared__ int sd[256];
    const int b = blockIdx.x, tid = threadIdx.x;
    int v = cntmat[b * NWG_P + tid];
    sd[tid] = v;
    for (int off = 1; off < 256; off <<= 1) {
        __syncthreads();
        int t = (tid >= off) ? sd[tid - off] : 0;
        __syncthreads();
        sd[tid] += t;
    }
    __syncthreads();
    cntmat[b * NWG_P + tid] = sd[tid] - v;
    if (tid == 255) btot[b] = sd[255];
}

__global__ __launch_bounds__(512) void k_bscan2(const int* __restrict__ btot,
                                                int* __restrict__ bbase,
                                                int NB, int E) {
    __shared__ int sd[512];
    const int tid = threadIdx.x;
    int v = (tid < NB) ? btot[tid] : 0;
    sd[tid] = v;
    for (int off = 1; off < 512; off <<= 1) {
        __syncthreads();
        int t = (tid >= off) ? sd[tid - off] : 0;
        __syncthreads();
        sd[tid] += t;
    }
    __syncthreads();
    if (tid < NB) bbase[tid] = sd[tid] - v;
    if (tid == 0) bbase[NB] = E;
}

__global__ __launch_bounds__(1024) void k_scat(const int* __restrict__ ei,
                                               const int* __restrict__ cntmat,
                                               const int* __restrict__ bbase,
                                               unsigned* __restrict__ tmp,
                                               int E, int NB, int per_wg) {
    __shared__ int lcur[NB_MAX];
    const int tid = threadIdx.x, wg = blockIdx.x;
    for (int b = tid; b < NB; b += 1024)
        lcur[b] = cntmat[b * NWG_P + wg] + bbase[b];
    __syncthreads();
    const int r0 = wg * per_wg, r1 = min(E, r0 + per_wg);
    for (int e = r0 + tid; e < r1; e += 1024) {
        int s = ei[e], d = ei[E + e];
        int b = d >> 8;
        int pos = atomicAdd(&lcur[b], 1);
        tmp[pos] = ((unsigned)(d & 255) << 24) | (unsigned)s;
    }
}

// P2: one WG per bucket. Self-inclusive adjacency; ssrc holds BYTE offsets
// (node * 128B) for the gather's 128B fp16 rows.
__global__ __launch_bounds__(256) void k_p2(const unsigned* __restrict__ tmp,
                                            const int* __restrict__ bbase,
                                            int* __restrict__ rstart,
                                            int* __restrict__ cnt,
                                            float* __restrict__ dinv,
                                            int* __restrict__ ssrc, int N) {
    __shared__ int nh[256];
    __shared__ int sd[256];
    __shared__ int curs[256];
    const int tid = threadIdx.x;
    const int b = blockIdx.x;
    const int node0 = b << 8;
    const int e0 = bbase[b], e1 = bbase[b + 1];
    nh[tid] = 0;
    __syncthreads();
    for (int e = e0 + tid; e < e1; e += 256)
        atomicAdd(&nh[tmp[e] >> 24], 1);
    __syncthreads();
    int v = nh[tid];
    sd[tid] = v;
    for (int off = 1; off < 256; off <<= 1) {
        __syncthreads();
        int t = (tid >= off) ? sd[tid - off] : 0;
        __syncthreads();
        sd[tid] += t;
    }
    __syncthreads();
    int rs = e0 + node0 + (sd[tid] - v) + tid;
    int node = node0 + tid;
    if (node < N) {
        rstart[node] = rs;
        cnt[node] = v + 1;                 // self-inclusive
        dinv[node] = rsqrtf((float)v + 1.0f);
        ssrc[rs] = node << 7;              // self entry (byte offset)
    }
    curs[tid] = rs + 1;
    __syncthreads();
    for (int e = e0 + tid; e < e1; e += 256) {
        unsigned p = tmp[e];
        int slot = atomicAdd(&curs[p >> 24], 1);
        ssrc[slot] = (int)(p & 0xFFFFFFu) << 7;   // byte offset
    }
}

// xh = fp16(dinv ⊙ x): 4 elems per thread.
__global__ __launch_bounds__(256) void k_prescale(const float* __restrict__ x,
                                                  const float* __restrict__ dinv,
                                                  _Float16* __restrict__ xh, int N) {
    int idx = blockIdx.x * 256 + threadIdx.x;   // over N*16
    if (idx >= N * 16) return;
    int i = idx >> 4;
    float dv = dinv[i];
    float4 v = *(const float4*)&x[(size_t)idx * 4];
    half4v o;
    o[0] = (_Float16)(dv * v.x); o[1] = (_Float16)(dv * v.y);
    o[2] = (_Float16)(dv * v.z); o[3] = (_Float16)(dv * v.w);
    *(half4v*)(xh + (size_t)idx * 4) = o;
}

// Prep W1/W2 into MFMA B-fragment-ordered fp16 buffers.
__global__ __launch_bounds__(256) void k_prep(const float* __restrict__ W1,
                                              const float* __restrict__ W2,
                                              _Float16* __restrict__ w1f,
                                              _Float16* __restrict__ w2f) {
    const int idx = blockIdx.x * 256 + threadIdx.x;
    if (idx < 1024) {                       // W1: nt 0..7, kk 0..1, lane
        const int lane = idx & 63;
        const int kk = (idx >> 6) & 1;
        const int nt = idx >> 7;
        const int quad = lane >> 4, col = lane & 15;
        half8 o;
#pragma unroll
        for (int j = 0; j < 8; ++j) {
            const int k = kk * 32 + quad * 8 + j;
            const int n = nt * 16 + col;
            o[j] = (_Float16)W1[k * HID + n];
        }
        *(half8*)(w1f + (size_t)idx * 8) = o;
    } else if (idx < 1024 + 768) {          // W2: nt 0..2, kk 0..3, lane (n pad 48)
        const int i2 = idx - 1024;
        const int lane = i2 & 63;
        const int kk = (i2 >> 6) & 3;
        const int nt = i2 >> 8;
        const int quad = lane >> 4, col = lane & 15;
        half8 o;
#pragma unroll
        for (int j = 0; j < 8; ++j) {
            const int k = kk * 32 + quad * 8 + j;
            const int n = nt * 16 + col;
            o[j] = (n < CLS) ? (_Float16)W2[k * CLS + n] : (_Float16)0.f;
        }
        *(half8*)(w2f + (size_t)i2 * 8) = o;
    }
}

// ---------------- packed fp16 gather (pk_add accumulate) ----------------
// X: fp16 rows of 64 halves (128B). One wave per dst row. Lane l: edge-slot
// group grp=l>>3, 16B chunk sub=l&7; one dwordx4 covers 8 edge rows.
// ssrc entries are BYTE offsets. Accumulate in 4x half2 (v_pk_add_f16);
// packed shfl_xor reduction; fp32 only in the epilogue.

template <bool HALF_OUT, int FOUT, bool BIAS>
__global__ __launch_bounds__(256) void k_gather16(const _Float16* __restrict__ X,
                                                  const float* __restrict__ dinv,
                                                  const int* __restrict__ rstart,
                                                  const int* __restrict__ cnt,
                                                  const int* __restrict__ ssrc,
                                                  const float* __restrict__ bias,
                                                  void* __restrict__ outv, int N) {
    const int wid = (blockIdx.x * 256 + threadIdx.x) >> 6;
    const int lane = threadIdx.x & 63;
    if (wid >= N) return;
    const int grp = lane >> 3, sub = lane & 7;
    const float dv = dinv[wid];
    const int st = rstart[wid];
    const int total = cnt[wid];            // self-inclusive
    const char* Xb = (const char*)X;
    half2v acc2[4] = {half2v{0, 0}, half2v{0, 0}, half2v{0, 0}, half2v{0, 0}};
    for (int base = 0; base < total; base += 64) {
        const int m = min(64, total - base);
        const int myO = (lane < m) ? ssrc[st + base + lane] : 0;
        const int gfull = m >> 3;
#pragma unroll 4
        for (int g = 0; g < gfull; ++g) {
            const int off = __shfl(myO, g * 8 + grp);
            const half8 hv = *(const half8*)(Xb + off + (sub << 4));
            const half2v* h2 = (const half2v*)&hv;
            acc2[0] += h2[0]; acc2[1] += h2[1];
            acc2[2] += h2[2]; acc2[3] += h2[3];
        }
        if (m & 7) {
            const int slot = gfull * 8 + grp;
            const int off = __shfl(myO, min(slot, m - 1));
            const _Float16 w = (slot < m) ? (_Float16)1 : (_Float16)0;
            const half2v w2 = {w, w};
            const half8 hv = *(const half8*)(Xb + off + (sub << 4));
            const half2v* h2 = (const half2v*)&hv;
#pragma unroll
            for (int i = 0; i < 4; ++i) acc2[i] = h2[i] * w2 + acc2[i];
        }
    }
#pragma unroll
    for (int i = 0; i < 4; ++i) {
        int t;
        t = __shfl_xor(*(const int*)&acc2[i], 8);  acc2[i] += *(const half2v*)&t;
        t = __shfl_xor(*(const int*)&acc2[i], 16); acc2[i] += *(const half2v*)&t;
        t = __shfl_xor(*(const int*)&acc2[i], 32); acc2[i] += *(const half2v*)&t;
    }
    float acc[8];
#pragma unroll
    for (int k = 0; k < 8; ++k) acc[k] = (float)acc2[k >> 1][k & 1];
    if (HALF_OUT) {
        if (grp == 0) {                    // lanes 0..7 write feats sub*8..+7
            half8 o;
#pragma unroll
            for (int k = 0; k < 8; ++k) o[k] = (_Float16)(acc[k] * dv);
            *(half8*)((_Float16*)outv + ((size_t)wid << 6) + (sub << 3)) = o;
        }
    } else {
        const int f0 = sub * 8 + (grp & 1) * 4;
        if (grp < 2 && f0 < FOUT) {
            const int k0 = (grp & 1) * 4;
            float4 o = make_float4(acc[k0] * dv, acc[k0 + 1] * dv,
                                   acc[k0 + 2] * dv, acc[k0 + 3] * dv);
            if (BIAS) {
                float4 bb = *(const float4*)&bias[f0];
                o.x += bb.x; o.y += bb.y; o.z += bb.z; o.w += bb.w;
            }
            *(float4*)((float*)outv + (size_t)wid * FOUT + f0) = o;
        }
    }
}

// ---------------- fused MFMA MLP: t -> h (regs) -> yh ----------------

__global__ __launch_bounds__(256, 3) void k_mlp(const _Float16* __restrict__ th,
                                                const _Float16* __restrict__ w1f,
                                                const float* __restrict__ b1,
                                                const _Float16* __restrict__ w2f,
                                                const float* __restrict__ dinv,
                                                _Float16* __restrict__ yh, int N) {
    __shared__ _Float16 hbuf[4][16 * 128];  // 16 KB
    const int tid = threadIdx.x;
    const int wave = tid >> 6, lane = tid & 63;
    const int quad = lane >> 4, col = lane & 15;
    const int row0 = blockIdx.x * 64 + wave * 16;
    const int arow = min(row0 + col, N - 1);
    const half8 a0 = *(const half8*)(th + ((size_t)arow << 6) + quad * 8);
    const half8 a1 = *(const half8*)(th + ((size_t)arow << 6) + 32 + quad * 8);
    floatx4 c[8];
#pragma unroll
    for (int nt = 0; nt < 8; ++nt) {
        c[nt] = (floatx4){0.f, 0.f, 0.f, 0.f};
        const half8 bb0 = *(const half8*)(w1f + (size_t)((nt * 2 + 0) * 64 + lane) * 8);
        const half8 bb1 = *(const half8*)(w1f + (size_t)((nt * 2 + 1) * 64 + lane) * 8);
        c[nt] = __builtin_amdgcn_mfma_f32_16x16x32_f16(a0, bb0, c[nt], 0, 0, 0);
        c[nt] = __builtin_amdgcn_mfma_f32_16x16x32_f16(a1, bb1, c[nt], 0, 0, 0);
    }
    _Float16* hb = hbuf[wave];
#pragma unroll
    for (int nt = 0; nt < 8; ++nt) {
        const float bv = b1[nt * 16 + col];
#pragma unroll
        for (int reg = 0; reg < 4; ++reg) {
            const int r = quad * 4 + reg;
            const int hcol = nt * 16 + col;
            const int chunk = ((hcol >> 3) ^ r) & 15;
            hb[r * 128 + chunk * 8 + (hcol & 7)] =
                (_Float16)fmaxf(c[nt][reg] + bv, 0.f);
        }
    }
    __syncthreads();
    half8 a2[4];
#pragma unroll
    for (int kk = 0; kk < 4; ++kk) {
        const int chunk = ((kk * 4 + quad) ^ col) & 15;
        a2[kk] = *(const half8*)(hb + col * 128 + chunk * 8);
    }
    floatx4 c2[3];
#pragma unroll
    for (int nt = 0; nt < 3; ++nt) {
        c2[nt] = (floatx4){0.f, 0.f, 0.f, 0.f};
#pragma unroll
        for (int kk = 0; kk < 4; ++kk) {
            const half8 bb = *(const half8*)(w2f + (size_t)((nt * 4 + kk) * 64 + lane) * 8);
            c2[nt] = __builtin_amdgcn_mfma_f32_16x16x32_f16(a2[kk], bb, c2[nt], 0, 0, 0);
        }
    }
#pragma unroll
    for (int reg = 0; reg < 4; ++reg) {
        const int gr = row0 + quad * 4 + reg;
        const float dvr = dinv[min(gr, N - 1)];
#pragma unroll
        for (int nt = 0; nt < 3; ++nt) {
            const int cc = nt * 16 + col;
            if (gr < N && cc < CLS)
                yh[((size_t)gr << 6) + cc] = (_Float16)(c2[nt][reg] * dvr);
        }
    }
    for (int i = lane; i < 16 * 12; i += 64) {
        const int row = row0 + i / 12;
        if (row < N)
            ((unsigned*)(yh + ((size_t)row << 6)))[20 + i % 12] = 0u;
    }
}

// ---------------- launch ----------------

extern "C" void kernel_launch(void* const* d_in, const int* in_sizes, int n_in,
                              void* d_out, int out_size, void* d_ws, size_t ws_size,
                              hipStream_t stream) {
    const float* x  = (const float*)d_in[0];
    const int*   ei = (const int*)d_in[1];   // [2][E]
    const float* W1 = (const float*)d_in[2];
    const float* b1 = (const float*)d_in[3];
    const float* W2 = (const float*)d_in[4];
    const float* b2 = (const float*)d_in[5];
    float* out = (float*)d_out;

    const int N = in_sizes[0] / FIN;
    const int E = in_sizes[1] / 2;
    const int NB = (N + 255) >> 8;
    const int per_wg = (E + NWG_P - 1) / NWG_P;

    float* dinv    = (float*)d_ws;                       // N
    _Float16* th   = (_Float16*)(dinv + N);              // N*64
    _Float16* yh   = th + (size_t)N * 64;                // N*64
    _Float16* xh   = yh + (size_t)N * 64;                // N*64
    int* cnt       = (int*)(xh + (size_t)N * 64);        // N
    int* rstart    = cnt + N;                            // N
    int* ssrc      = rstart + N;                         // E + N
    int* cntmat    = ssrc + E + N;                       // NB_MAX*NWG_P
    int* btot      = cntmat + NB_MAX * NWG_P;            // NB_MAX
    int* bbase     = btot + NB_MAX;                      // NB_MAX+1
    unsigned* tmp  = (unsigned*)(bbase + NB_MAX + 1);    // E
    _Float16* w1f  = (_Float16*)(tmp + E);               // 8192
    _Float16* w2f  = w1f + 8192;                         // 6144

    dim3 blk(256);
    // CSR build
    hipLaunchKernelGGL(k_cnt,    dim3(NWG_P), dim3(1024), 0, stream, ei + E, cntmat, E, NB, per_wg);
    hipLaunchKernelGGL(k_bscan1, dim3(NB), blk, 0, stream, cntmat, btot);
    hipLaunchKernelGGL(k_bscan2, dim3(1), dim3(512), 0, stream, btot, bbase, NB, E);
    hipLaunchKernelGGL(k_scat,   dim3(NWG_P), dim3(1024), 0, stream, ei, cntmat, bbase, tmp, E, NB, per_wg);
    hipLaunchKernelGGL(k_p2,     dim3(NB), blk, 0, stream, tmp, bbase, rstart, cnt, dinv, ssrc, N);
    // weight prep (fragment-ordered fp16)
    hipLaunchKernelGGL(k_prep, dim3(7), blk, 0, stream, W1, W2, w1f, w2f);
    // layer 1: prescale -> packed fp16 gather (fp16 out)
    hipLaunchKernelGGL(k_prescale, dim3((N * 16 + 255) / 256), blk, 0, stream, x, dinv, xh, N);
    hipLaunchKernelGGL((k_gather16<true, FIN, false>), dim3((N + 3) / 4), blk, 0, stream,
                       xh, dinv, rstart, cnt, ssrc, (const float*)nullptr, (void*)th, N);
    // fused MFMA MLP: t -> h -> yh
    hipLaunchKernelGGL(k_mlp, dim3((N + 63) / 64), blk, 0, stream, th, w1f, b1, w2f, dinv, yh, N);
    // layer 2 aggregate + bias -> out
    hipLaunchKernelGGL((k_gather16<false, CLS, true>), dim3((N + 3) / 4), blk, 0, stream,
                       yh, dinv, rstart, cnt, ssrc, b2, (void*)out, N);
}

// Round 11
// 199.322 us; speedup vs baseline: 1.5222x; 1.1227x over previous
//
#include <hip/hip_runtime.h>
#include <hip/hip_bf16.h>

// GCN 2-layer forward on gfx950 — CSR radix partition, group-per-row packed
// fp16 gathers (no cross-lane reduction), fused fp16-MFMA MLP.
//
//   xh = fp16(dinv ⊙ x)            (row N = zeros, the OOB target)
//   t  = fp16( dinv[d] * Σ_{s∈csr[d]} xh[s] )     (gather, self-inclusive)
//   h  = relu(t W1 + b1)   [MFMA, C-frags in regs]
//   yh = fp16(dinv ⊙ (h W2)) padded to 64 cols    (row N = zeros)
//   out[d] = dinv[d] * Σ yh[s] + b2               (gather)
//
// R11: R10 gather still 46.6us (VALU 53%) — per-row epilogue reduction
// (12 bperm + 12 pk_add + 8 cvt) rivals the 3-group main loop on avg-17
// rows. New layout: 8-lane group owns a whole dst row; lane owns a fixed
// 16B chunk; edges accumulate serially in-lane -> ZERO reduction. OOB
// slots load the zero row at index N (no masks in the inner loop).
// Memory floor (from R7/R8 A/B): ~31us/gather at 89MB fetch.

static constexpr int FIN = 64;
static constexpr int HID = 128;
static constexpr int CLS = 40;
static constexpr int NB_MAX = 392;   // buckets of 256 nodes; N <= 100352
static constexpr int NWG_P = 256;    // partition workgroups

typedef _Float16 half8 __attribute__((ext_vector_type(8)));
typedef _Float16 half4v __attribute__((ext_vector_type(4)));
typedef _Float16 half2v __attribute__((ext_vector_type(2)));
typedef float floatx4 __attribute__((ext_vector_type(4)));

// ---------------- CSR build: radix partition by dst>>8 ----------------

__global__ __launch_bounds__(1024) void k_cnt(const int* __restrict__ dst,
                                              int* __restrict__ cntmat,
                                              int E, int NB, int per_wg) {
    __shared__ int lh[NB_MAX];
    const int tid = threadIdx.x, wg = blockIdx.x;
    for (int i = tid; i < NB; i += 1024) lh[i] = 0;
    __syncthreads();
    const int r0 = wg * per_wg, r1 = min(E, r0 + per_wg);
    for (int e = r0 + tid; e < r1; e += 1024)
        atomicAdd(&lh[dst[e] >> 8], 1);
    __syncthreads();
    for (int b = tid; b < NB; b += 1024) cntmat[b * NWG_P + wg] = lh[b];
}

__global__ __launch_bounds__(256) void k_bscan1(int* __restrict__ cntmat,
                                                int* __restrict__ btot) {
    __shared__ int sd[256];
    const int b = blockIdx.x, tid = threadIdx.x;
    int v = cntmat[b * NWG_P + tid];
    sd[tid] = v;
    for (int off = 1; off < 256; off <<= 1) {
        __syncthreads();
        int t = (tid >= off) ? sd[tid - off] : 0;
        __syncthreads();
        sd[tid] += t;
    }
    __syncthreads();
    cntmat[b * NWG_P + tid] = sd[tid] - v;
    if (tid == 255) btot[b] = sd[255];
}

__global__ __launch_bounds__(512) void k_bscan2(const int* __restrict__ btot,
                                                int* __restrict__ bbase,
                                                int NB, int E) {
    __shared__ int sd[512];
    const int tid = threadIdx.x;
    int v = (tid < NB) ? btot[tid] : 0;
    sd[tid] = v;
    for (int off = 1; off < 512; off <<= 1) {
        __syncthreads();
        int t = (tid >= off) ? sd[tid - off] : 0;
        __syncthreads();
        sd[tid] += t;
    }
    __syncthreads();
    if (tid < NB) bbase[tid] = sd[tid] - v;
    if (tid == 0) bbase[NB] = E;
}

__global__ __launch_bounds__(1024) void k_scat(const int* __restrict__ ei,
                                               const int* __restrict__ cntmat,
                                               const int* __restrict__ bbase,
                                               unsigned* __restrict__ tmp,
                                               int E, int NB, int per_wg) {
    __shared__ int lcur[NB_MAX];
    const int tid = threadIdx.x, wg = blockIdx.x;
    for (int b = tid; b < NB; b += 1024)
        lcur[b] = cntmat[b * NWG_P + wg] + bbase[b];
    __syncthreads();
    const int r0 = wg * per_wg, r1 = min(E, r0 + per_wg);
    for (int e = r0 + tid; e < r1; e += 1024) {
        int s = ei[e], d = ei[E + e];
        int b = d >> 8;
        int pos = atomicAdd(&lcur[b], 1);
        tmp[pos] = ((unsigned)(d & 255) << 24) | (unsigned)s;
    }
}

// P2: one WG per bucket. Self-inclusive adjacency; ssrc holds BYTE offsets
// (node * 128B) into the 128B fp16 row arrays.
__global__ __launch_bounds__(256) void k_p2(const unsigned* __restrict__ tmp,
                                            const int* __restrict__ bbase,
                                            int* __restrict__ rstart,
                                            int* __restrict__ cnt,
                                            float* __restrict__ dinv,
                                            int* __restrict__ ssrc, int N) {
    __shared__ int nh[256];
    __shared__ int sd[256];
    __shared__ int curs[256];
    const int tid = threadIdx.x;
    const int b = blockIdx.x;
    const int node0 = b << 8;
    const int e0 = bbase[b], e1 = bbase[b + 1];
    nh[tid] = 0;
    __syncthreads();
    for (int e = e0 + tid; e < e1; e += 256)
        atomicAdd(&nh[tmp[e] >> 24], 1);
    __syncthreads();
    int v = nh[tid];
    sd[tid] = v;
    for (int off = 1; off < 256; off <<= 1) {
        __syncthreads();
        int t = (tid >= off) ? sd[tid - off] : 0;
        __syncthreads();
        sd[tid] += t;
    }
    __syncthreads();
    int rs = e0 + node0 + (sd[tid] - v) + tid;
    int node = node0 + tid;
    if (node < N) {
        rstart[node] = rs;
        cnt[node] = v + 1;                 // self-inclusive
        dinv[node] = rsqrtf((float)v + 1.0f);
        ssrc[rs] = node << 7;              // self entry (byte offset)
    }
    curs[tid] = rs + 1;
    __syncthreads();
    for (int e = e0 + tid; e < e1; e += 256) {
        unsigned p = tmp[e];
        int slot = atomicAdd(&curs[p >> 24], 1);
        ssrc[slot] = (int)(p & 0xFFFFFFu) << 7;   // byte offset
    }
}

// xh = fp16(dinv ⊙ x): 4 elems per thread.
__global__ __launch_bounds__(256) void k_prescale(const float* __restrict__ x,
                                                  const float* __restrict__ dinv,
                                                  _Float16* __restrict__ xh, int N) {
    int idx = blockIdx.x * 256 + threadIdx.x;   // over N*16
    if (idx >= N * 16) return;
    int i = idx >> 4;
    float dv = dinv[i];
    float4 v = *(const float4*)&x[(size_t)idx * 4];
    half4v o;
    o[0] = (_Float16)(dv * v.x); o[1] = (_Float16)(dv * v.y);
    o[2] = (_Float16)(dv * v.z); o[3] = (_Float16)(dv * v.w);
    *(half4v*)(xh + (size_t)idx * 4) = o;
}

// Zero the OOB target rows (index N) of xh and yh.
__global__ void k_zrows(_Float16* __restrict__ xh, _Float16* __restrict__ yh, int N) {
    int t = threadIdx.x;
    if (t < 64) {
        xh[(size_t)N * 64 + t] = (_Float16)0;
        yh[(size_t)N * 64 + t] = (_Float16)0;
    }
}

// Prep W1/W2 into MFMA B-fragment-ordered fp16 buffers.
__global__ __launch_bounds__(256) void k_prep(const float* __restrict__ W1,
                                              const float* __restrict__ W2,
                                              _Float16* __restrict__ w1f,
                                              _Float16* __restrict__ w2f) {
    const int idx = blockIdx.x * 256 + threadIdx.x;
    if (idx < 1024) {                       // W1: nt 0..7, kk 0..1, lane
        const int lane = idx & 63;
        const int kk = (idx >> 6) & 1;
        const int nt = idx >> 7;
        const int quad = lane >> 4, col = lane & 15;
        half8 o;
#pragma unroll
        for (int j = 0; j < 8; ++j) {
            const int k = kk * 32 + quad * 8 + j;
            const int n = nt * 16 + col;
            o[j] = (_Float16)W1[k * HID + n];
        }
        *(half8*)(w1f + (size_t)idx * 8) = o;
    } else if (idx < 1024 + 768) {          // W2: nt 0..2, kk 0..3, lane (n pad 48)
        const int i2 = idx - 1024;
        const int lane = i2 & 63;
        const int kk = (i2 >> 6) & 3;
        const int nt = i2 >> 8;
        const int quad = lane >> 4, col = lane & 15;
        half8 o;
#pragma unroll
        for (int j = 0; j < 8; ++j) {
            const int k = kk * 32 + quad * 8 + j;
            const int n = nt * 16 + col;
            o[j] = (n < CLS) ? (_Float16)W2[k * CLS + n] : (_Float16)0.f;
        }
        *(half8*)(w2f + (size_t)i2 * 8) = o;
    }
}

// ---------------- group-per-row packed fp16 gather ----------------
// X: fp16 rows of 64 halves (128B), row N = zeros. Wave handles 8 rows:
// group g (8 lanes) owns row wave*8+g; lane's chunk sub = 16B. Edges
// accumulate serially in-lane (4 pk_add per edge) — no reduction. OOB
// slots broadcast the zero-row offset. ssrc entries are BYTE offsets.

template <bool HALF_OUT, int FOUT, bool BIAS>
__global__ __launch_bounds__(256) void k_gather8(const _Float16* __restrict__ X,
                                                 const float* __restrict__ dinv,
                                                 const int* __restrict__ rstart,
                                                 const int* __restrict__ cnt,
                                                 const int* __restrict__ ssrc,
                                                 const float* __restrict__ bias,
                                                 void* __restrict__ outv,
                                                 int N, int zoff) {
    const int wave = (blockIdx.x * 256 + threadIdx.x) >> 6;
    const int lane = threadIdx.x & 63;
    const int g = lane >> 3, sub = lane & 7;
    const int r = wave * 8 + g;
    const int rc = min(r, N - 1);
    const int st = rstart[rc];
    const int total = cnt[rc];             // self-inclusive, >= 1
    int maxtot = total;                    // wave-max iteration bound
    maxtot = max(maxtot, __shfl_xor(maxtot, 8));
    maxtot = max(maxtot, __shfl_xor(maxtot, 16));
    maxtot = max(maxtot, __shfl_xor(maxtot, 32));
    const char* Xb = (const char*)X;
    half2v acc2[4] = {half2v{0, 0}, half2v{0, 0}, half2v{0, 0}, half2v{0, 0}};
    for (int base = 0; base < maxtot; base += 8) {
        const int idx = base + sub;
        int myO = ssrc[st + min(idx, total - 1)];
        myO = (idx < total) ? myO : zoff;  // OOB -> zero row
#pragma unroll
        for (int jj = 0; jj < 8; ++jj) {
            const int off = __shfl(myO, g * 8 + jj);
            const half8 hv = *(const half8*)(Xb + off + (sub << 4));
            const half2v* h2 = (const half2v*)&hv;
            acc2[0] += h2[0]; acc2[1] += h2[1];
            acc2[2] += h2[2]; acc2[3] += h2[3];
        }
    }
    if (r >= N) return;
    const float dv = dinv[rc];
    float acc[8];
#pragma unroll
    for (int k = 0; k < 8; ++k) acc[k] = (float)acc2[k >> 1][k & 1] * dv;
    if (HALF_OUT) {
        half8 o;
#pragma unroll
        for (int k = 0; k < 8; ++k) o[k] = (_Float16)acc[k];
        *(half8*)((_Float16*)outv + ((size_t)r << 6) + (sub << 3)) = o;
    } else {
        const int f0 = sub * 8;
        if (f0 < FOUT) {
            if (BIAS) {
                float4 bb0 = *(const float4*)&bias[f0];
                float4 bb1 = *(const float4*)&bias[f0 + 4];
                acc[0] += bb0.x; acc[1] += bb0.y; acc[2] += bb0.z; acc[3] += bb0.w;
                acc[4] += bb1.x; acc[5] += bb1.y; acc[6] += bb1.z; acc[7] += bb1.w;
            }
            float* op = (float*)outv + (size_t)r * FOUT + f0;
            *(float4*)op = make_float4(acc[0], acc[1], acc[2], acc[3]);
            *(float4*)(op + 4) = make_float4(acc[4], acc[5], acc[6], acc[7]);
        }
    }
}

// ---------------- fused MFMA MLP: t -> h (regs) -> yh ----------------

__global__ __launch_bounds__(256, 3) void k_mlp(const _Float16* __restrict__ th,
                                                const _Float16* __restrict__ w1f,
                                                const float* __restrict__ b1,
                                                const _Float16* __restrict__ w2f,
                                                const float* __restrict__ dinv,
                                                _Float16* __restrict__ yh, int N) {
    __shared__ _Float16 hbuf[4][16 * 128];  // 16 KB
    const int tid = threadIdx.x;
    const int wave = tid >> 6, lane = tid & 63;
    const int quad = lane >> 4, col = lane & 15;
    const int row0 = blockIdx.x * 64 + wave * 16;
    const int arow = min(row0 + col, N - 1);
    const half8 a0 = *(const half8*)(th + ((size_t)arow << 6) + quad * 8);
    const half8 a1 = *(const half8*)(th + ((size_t)arow << 6) + 32 + quad * 8);
    floatx4 c[8];
#pragma unroll
    for (int nt = 0; nt < 8; ++nt) {
        c[nt] = (floatx4){0.f, 0.f, 0.f, 0.f};
        const half8 bb0 = *(const half8*)(w1f + (size_t)((nt * 2 + 0) * 64 + lane) * 8);
        const half8 bb1 = *(const half8*)(w1f + (size_t)((nt * 2 + 1) * 64 + lane) * 8);
        c[nt] = __builtin_amdgcn_mfma_f32_16x16x32_f16(a0, bb0, c[nt], 0, 0, 0);
        c[nt] = __builtin_amdgcn_mfma_f32_16x16x32_f16(a1, bb1, c[nt], 0, 0, 0);
    }
    _Float16* hb = hbuf[wave];
#pragma unroll
    for (int nt = 0; nt < 8; ++nt) {
        const float bv = b1[nt * 16 + col];
#pragma unroll
        for (int reg = 0; reg < 4; ++reg) {
            const int r = quad * 4 + reg;
            const int hcol = nt * 16 + col;
            const int chunk = ((hcol >> 3) ^ r) & 15;
            hb[r * 128 + chunk * 8 + (hcol & 7)] =
                (_Float16)fmaxf(c[nt][reg] + bv, 0.f);
        }
    }
    __syncthreads();
    half8 a2[4];
#pragma unroll
    for (int kk = 0; kk < 4; ++kk) {
        const int chunk = ((kk * 4 + quad) ^ col) & 15;
        a2[kk] = *(const half8*)(hb + col * 128 + chunk * 8);
    }
    floatx4 c2[3];
#pragma unroll
    for (int nt = 0; nt < 3; ++nt) {
        c2[nt] = (floatx4){0.f, 0.f, 0.f, 0.f};
#pragma unroll
        for (int kk = 0; kk < 4; ++kk) {
            const half8 bb = *(const half8*)(w2f + (size_t)((nt * 4 + kk) * 64 + lane) * 8);
            c2[nt] = __builtin_amdgcn_mfma_f32_16x16x32_f16(a2[kk], bb, c2[nt], 0, 0, 0);
        }
    }
#pragma unroll
    for (int reg = 0; reg < 4; ++reg) {
        const int gr = row0 + quad * 4 + reg;
        const float dvr = dinv[min(gr, N - 1)];
#pragma unroll
        for (int nt = 0; nt < 3; ++nt) {
            const int cc = nt * 16 + col;
            if (gr < N && cc < CLS)
                yh[((size_t)gr << 6) + cc] = (_Float16)(c2[nt][reg] * dvr);
        }
    }
    for (int i = lane; i < 16 * 12; i += 64) {
        const int row = row0 + i / 12;
        if (row < N)
            ((unsigned*)(yh + ((size_t)row << 6)))[20 + i % 12] = 0u;
    }
}

// ---------------- launch ----------------

extern "C" void kernel_launch(void* const* d_in, const int* in_sizes, int n_in,
                              void* d_out, int out_size, void* d_ws, size_t ws_size,
                              hipStream_t stream) {
    const float* x  = (const float*)d_in[0];
    const int*   ei = (const int*)d_in[1];   // [2][E]
    const float* W1 = (const float*)d_in[2];
    const float* b1 = (const float*)d_in[3];
    const float* W2 = (const float*)d_in[4];
    const float* b2 = (const float*)d_in[5];
    float* out = (float*)d_out;

    const int N = in_sizes[0] / FIN;
    const int E = in_sizes[1] / 2;
    const int NB = (N + 255) >> 8;
    const int per_wg = (E + NWG_P - 1) / NWG_P;
    const int zoff = N << 7;                 // zero-row byte offset

    float* dinv    = (float*)d_ws;                       // N
    _Float16* th   = (_Float16*)(dinv + N);              // (N+1)*64
    _Float16* yh   = th + (size_t)(N + 1) * 64;          // (N+1)*64
    _Float16* xh   = yh + (size_t)(N + 1) * 64;          // (N+1)*64
    int* cnt       = (int*)(xh + (size_t)(N + 1) * 64);  // N
    int* rstart    = cnt + N;                            // N
    int* ssrc      = rstart + N;                         // E + N
    int* cntmat    = ssrc + E + N;                       // NB_MAX*NWG_P
    int* btot      = cntmat + NB_MAX * NWG_P;            // NB_MAX
    int* bbase     = btot + NB_MAX;                      // NB_MAX+1
    unsigned* tmp  = (unsigned*)(bbase + NB_MAX + 1);    // E
    _Float16* w1f  = (_Float16*)(tmp + E);               // 8192
    _Float16* w2f  = w1f + 8192;                         // 6144

    dim3 blk(256);
    // CSR build
    hipLaunchKernelGGL(k_cnt,    dim3(NWG_P), dim3(1024), 0, stream, ei + E, cntmat, E, NB, per_wg);
    hipLaunchKernelGGL(k_bscan1, dim3(NB), blk, 0, stream, cntmat, btot);
    hipLaunchKernelGGL(k_bscan2, dim3(1), dim3(512), 0, stream, btot, bbase, NB, E);
    hipLaunchKernelGGL(k_scat,   dim3(NWG_P), dim3(1024), 0, stream, ei, cntmat, bbase, tmp, E, NB, per_wg);
    hipLaunchKernelGGL(k_p2,     dim3(NB), blk, 0, stream, tmp, bbase, rstart, cnt, dinv, ssrc, N);
    // weight prep + zero rows
    hipLaunchKernelGGL(k_prep,  dim3(7), blk, 0, stream, W1, W2, w1f, w2f);
    hipLaunchKernelGGL(k_zrows, dim3(1), dim3(64), 0, stream, xh, yh, N);
    // layer 1: prescale -> group-per-row gather (fp16 out)
    hipLaunchKernelGGL(k_prescale, dim3((N * 16 + 255) / 256), blk, 0, stream, x, dinv, xh, N);
    hipLaunchKernelGGL((k_gather8<true, FIN, false>), dim3((N + 31) / 32), blk, 0, stream,
                       xh, dinv, rstart, cnt, ssrc, (const float*)nullptr, (void*)th, N, zoff);
    // fused MFMA MLP: t -> h -> yh
    hipLaunchKernelGGL(k_mlp, dim3((N + 63) / 64), blk, 0, stream, th, w1f, b1, w2f, dinv, yh, N);
    // layer 2 aggregate + bias -> out
    hipLaunchKernelGGL((k_gather8<false, CLS, true>), dim3((N + 31) / 32), blk, 0, stream,
                       yh, dinv, rstart, cnt, ssrc, b2, (void*)out, N, zoff);
}